// Round 13
// baseline (2203.724 us; speedup 1.0000x reference)
//
#include <hip/hip_runtime.h>
#include <math.h>
#include <stdint.h>

#define DIM 256
#define NUME 4096
#define NTOK 32768
#define NELEM 8388608        // 32*256*32*32
#define LOSS_OFF 8388608
#define PERP_OFF 8388609
#define IDX_OFF  8388610
#define MARGIN   8.0e-4f     // score-space margin (i8: 2x bf16's, >>18 sigma)
#define PAD_M    2.0e-4f     // extra m-space pad
#define CAND_CAP 48
#define BOOT_TILES 32        // bootstrap sample: 2048 codes

// i8 scale chain: w_true = wq/(127*4096); x_true ~ xq*(6/127)
// m_true = acc * S,  S = 6/(127*127*4096)
#define INV_S    11010730.67f
#define S_F      9.0820578e-8f

using int32x4 = __attribute__((ext_vector_type(4))) int;
using i32x16  = __attribute__((ext_vector_type(16))) int;

#define WAIT_VM4()   do { asm volatile("s_waitcnt vmcnt(4)" ::: "memory"); \
                          __builtin_amdgcn_sched_barrier(0); } while (0)
#define WAIT_VM0()   do { asm volatile("s_waitcnt vmcnt(0)" ::: "memory"); \
                          __builtin_amdgcn_sched_barrier(0); } while (0)
#define WAIT_LGKM0() do { asm volatile("s_waitcnt lgkmcnt(0)" ::: "memory"); \
                          __builtin_amdgcn_sched_barrier(0); } while (0)
#define BAR()        __builtin_amdgcn_s_barrier()

__device__ __forceinline__ void gload_lds16(const void* g, void* l) {
    __builtin_amdgcn_global_load_lds(
        (const __attribute__((address_space(1))) void*)g,
        (__attribute__((address_space(3))) void*)l, 16, 0, 0);
}
__device__ __forceinline__ int qx8(float v) {   // x -> i8, fixed scale 127/6
    return (int)rintf(fminf(fmaxf(v, -6.f), 6.f) * 21.166666667f);
}
__device__ __forceinline__ uint32_t pack4(int q0, int q1, int q2, int q3) {
    return  (uint32_t)(uint8_t)(int8_t)q0        |
           ((uint32_t)(uint8_t)(int8_t)q1 <<  8) |
           ((uint32_t)(uint8_t)(int8_t)q2 << 16) |
           ((uint32_t)(uint8_t)(int8_t)q3 << 24);
}

// ---------------- prep: W fp32 -> i8 [4096][256], scale 127*4096 ----------------
__global__ void vq_prep(const float* __restrict__ w, uint8_t* __restrict__ wb) {
    int gid = blockIdx.x * 256 + threadIdx.x;       // 131072 threads x 8 elems
    const float4* src = (const float4*)(w + (size_t)gid * 8);
    float4 a = src[0], c = src[1];
    auto q = [](float v) -> int {
        return (int)rintf(fminf(fmaxf(v * 520192.f, -127.f), 127.f));
    };
    uint2 o;
    o.x = pack4(q(a.x), q(a.y), q(a.z), q(a.w));
    o.y = pack4(q(c.x), q(c.y), q(c.z), q(c.w));
    *(uint2*)(wb + (size_t)gid * 8) = o;
}

// ---- main: i8 screen (boot-32 -> frozen thr -> collect-64) + exact fp32 rescore ----
__global__ __launch_bounds__(256, 3)
void vq_mfma(const float* __restrict__ x, const float* __restrict__ wt,
             const uint8_t* __restrict__ wb, float* __restrict__ out,
             int* __restrict__ counts, float* __restrict__ partials) {
    __shared__ __align__(16) char UB[32768];   // union: X-i8 [64][256] / W dbuf / Xf32 chunk
    __shared__ float sxp[4][64];
    __shared__ float sxS[64];
    __shared__ unsigned gmU[64];
    __shared__ unsigned candCnt[64];
    __shared__ unsigned candL[64 * CAND_CAP];
    __shared__ int wIdxS[64];
    __shared__ float lred[4];

    const int t    = threadIdx.x;
    const int lane = t & 63;
    const int wv   = t >> 6;                 // wave 0..3
    const int wr   = wv >> 1, wc = wv & 1;   // wave grid 2x2 (32 tok x 32 code)
    const int l31  = lane & 31, hh = lane >> 5;
    const int wg   = blockIdx.x;
    const int n0   = wg << 6;
    const int b    = n0 >> 10;
    const int p0   = n0 & 1023;
    const float* xbase = x + (size_t)b * (DIM * 1024) + p0;

    if (t < 64) { gmU[t] = 0x7F7FFFFFu; candCnt[t] = 0; }

    // ---- S0': single x pass: sx partial + quantize+pack X-i8 into UB ----
    {
        int tok = t & 63, w8 = t >> 6;
        const float* p = xbase + (size_t)(w8 * 64) * 1024 + tok;
        float s = 0.f;
        #pragma unroll
        for (int dq = 0; dq < 16; ++dq) {
            float v0 = p[(size_t)(dq * 4 + 0) * 1024];
            float v1 = p[(size_t)(dq * 4 + 1) * 1024];
            float v2 = p[(size_t)(dq * 4 + 2) * 1024];
            float v3 = p[(size_t)(dq * 4 + 3) * 1024];
            s = fmaf(v0, v0, s); s = fmaf(v1, v1, s);
            s = fmaf(v2, v2, s); s = fmaf(v3, v3, s);
            uint32_t pk = pack4(qx8(v0), qx8(v1), qx8(v2), qx8(v3));
            int byte = tok * 256 + w8 * 64 + dq * 4;
            byte ^= ((tok & 15) << 4);
            *(uint32_t*)(UB + byte) = pk;
        }
        sxp[w8][tok] = s;
    }
    __syncthreads();
    if (t < 64) sxS[t] = (sxp[0][t] + sxp[1][t]) + (sxp[2][t] + sxp[3][t]);

    // ---- S2: A-frags (i8 32x32x32 layout) resident in registers ----
    int32x4 aF[8];
    #pragma unroll
    for (int ks = 0; ks < 8; ++ks) {
        int row = wr * 32 + l31;
        int byte = (row * 256 + (ks << 5) + (hh << 4)) ^ ((row & 15) << 4);
        aF[ks] = *(const int32x4*)(UB + byte);
    }
    __syncthreads();   // X-i8 dead; UB free for W staging

    auto STAGE = [&](int k0, int half) {
        #pragma unroll
        for (int i = 0; i < 4; ++i) {
            int o16 = i * 256 + t;                 // 16B-chunk index, 1024 per half
            int code = o16 >> 4, u = o16 & 15;
            const char* src = (const char*)wb + ((size_t)(k0 + code) << 8)
                              + ((u ^ (code & 15)) << 4);
            gload_lds16(src, UB + (half << 14) + (o16 << 4));
        }
    };

    // ---- bootstrap: tiles 0..31, pure register max; depth-2 pipeline ----
    float run[16];
    #pragma unroll
    for (int rg = 0; rg < 16; ++rg) run[rg] = -3.0e38f;

    STAGE(0, 0);
    STAGE(64, 1);
    for (int tile = 0; tile < BOOT_TILES; ++tile) {
        if (tile < BOOT_TILES - 1) WAIT_VM4(); else WAIT_VM0();
        BAR();
        const int half = tile & 1;

        i32x16 acc = {0,0,0,0,0,0,0,0,0,0,0,0,0,0,0,0};
        const int cr = wc * 32 + l31;
        const int bbase = (half << 14) + cr * 256 + (hh << 4);
        const int bxor  = ((cr & 15) << 4);
        #pragma unroll
        for (int ks = 0; ks < 8; ++ks) {
            int32x4 bF = *(const int32x4*)(UB + ((bbase + (ks << 5)) ^ bxor));
            acc = __builtin_amdgcn_mfma_i32_32x32x32_i8(aF[ks], bF, acc, 0, 0, 0);
        }
        #pragma unroll
        for (int rg = 0; rg < 16; ++rg) run[rg] = fmaxf(run[rg], (float)acc[rg]);

        WAIT_LGKM0();
        BAR();
        if (tile + 2 < BOOT_TILES) STAGE((tile + 2) * 64, half);
    }

    // reduce bootstrap row maxes (int-exact as floats) over 32 lanes per row
    #pragma unroll
    for (int rg = 0; rg < 16; ++rg) {
        float m = run[rg];
        #pragma unroll
        for (int sh = 1; sh < 32; sh <<= 1) m = fmaxf(m, __shfl_xor(m, sh, 64));
        if (l31 == 0) {
            int row = wr * 32 + (rg & 3) + 8 * (rg >> 2) + 4 * hh;
            float s = sxS[row] - 2.0f * (m * S_F);   // s-space lower bound
            atomicMin(&gmU[row], __float_as_uint(s));
        }
    }
    __syncthreads();

    // frozen conservative threshold in INT units
    float athr[16];
    #pragma unroll
    for (int rg = 0; rg < 16; ++rg) {
        int row = wr * 32 + (rg & 3) + 8 * (rg >> 2) + 4 * hh;
        athr[rg] = (0.5f * (sxS[row] - (__uint_as_float(gmU[row]) + MARGIN)) - PAD_M)
                   * INV_S;
    }

    // ---- collect sweep: 64 tiles vs FIXED threshold; depth-2 pipeline ----
    STAGE(0, 0);
    STAGE(64, 1);
    for (int tile = 0; tile < 64; ++tile) {
        if (tile < 63) WAIT_VM4(); else WAIT_VM0();
        BAR();
        const int half = tile & 1;

        i32x16 acc = {0,0,0,0,0,0,0,0,0,0,0,0,0,0,0,0};
        const int cr = wc * 32 + l31;
        const int bbase = (half << 14) + cr * 256 + (hh << 4);
        const int bxor  = ((cr & 15) << 4);
        #pragma unroll
        for (int ks = 0; ks < 8; ++ks) {
            int32x4 bF = *(const int32x4*)(UB + ((bbase + (ks << 5)) ^ bxor));
            acc = __builtin_amdgcn_mfma_i32_32x32x32_i8(aF[ks], bF, acc, 0, 0, 0);
        }
        #pragma unroll
        for (int rg = 0; rg < 16; ++rg) {
            if ((float)acc[rg] >= athr[rg]) {
                int row = wr * 32 + (rg & 3) + 8 * (rg >> 2) + 4 * hh;
                int code = tile * 64 + wc * 32 + l31;
                unsigned s = atomicAdd(&candCnt[row], 1u);
                if (s < CAND_CAP) candL[row * CAND_CAP + s] = (unsigned)code;
            }
        }

        WAIT_LGKM0();
        BAR();
        if (tile + 2 < 64) STAGE((tile + 2) * 64, half);
    }

    // ---- chunked exact fp32 rescore + fused epilogue (16-token chunks x4) ----
    float sqAcc = 0.f;
    for (int ch = 0; ch < 4; ++ch) {
        __syncthreads();
        {   // stage Xf32 [16][258] (padded) into UB
            int dg = t >> 1, c = t & 1;
            #pragma unroll
            for (int it = 0; it < 2; ++it) {
                int d = it * 128 + dg;
                const float* row = xbase + (size_t)d * 1024 + ch * 16 + c * 8;
                float4 f0 = *(const float4*)(row);
                float4 f1 = *(const float4*)(row + 4);
                float vv[8] = {f0.x, f0.y, f0.z, f0.w, f1.x, f1.y, f1.z, f1.w};
                #pragma unroll
                for (int j = 0; j < 8; ++j) {
                    int tl = c * 8 + j;
                    *(float*)(UB + ((tl * 258 + d) << 2)) = vv[j];
                }
            }
        }
        __syncthreads();
        // rescore: wave-per-token, reference-exact fl(sx - 2*dot), lowest-index ties
        for (int tl = wv; tl < 16; tl += 4) {
            int tok = ch * 16 + tl;
            unsigned ncnt = candCnt[tok];
            bool ovf = ncnt > CAND_CAP;                 // ~never: exact full scan
            int count = ovf ? NUME : (int)ncnt;
            float bs = 3.0e38f; int bi = 0;
            for (int ci = 0; ci < count; ++ci) {
                int code = ovf ? ci : (int)candL[tok * CAND_CAP + ci];
                float4 wv4 = *(const float4*)(wt + (size_t)code * 256 + lane * 4);
                const float* xr = (const float*)(UB + ((tl * 258 + lane * 4) << 2));
                float p = wv4.x * xr[0];
                p = fmaf(wv4.y, xr[1], p);
                p = fmaf(wv4.z, xr[2], p);
                p = fmaf(wv4.w, xr[3], p);
                #pragma unroll
                for (int sh = 1; sh < 64; sh <<= 1) p += __shfl_xor(p, sh, 64);
                float s = sxS[tok] - 2.0f * p;
                if (s < bs || (s == bs && code < bi)) { bs = s; bi = code; }
            }
            if (lane == 0) wIdxS[tok] = bi;
        }
        __syncthreads();
        {   // gather + quantized write + loss partial
            int tl = t & 15, db = (t >> 4) * 16;
            int idx = wIdxS[ch * 16 + tl];
            const float* wrow = wt + (size_t)idx * 256;
            float* op = out + (size_t)b * (DIM * 1024) + p0 + ch * 16 + tl;
            #pragma unroll
            for (int j = 0; j < 4; ++j) {
                int d = db + 4 * j;
                float4 q4 = *(const float4*)(wrow + d);
                const float* xr = (const float*)(UB + ((tl * 258 + d) << 2));
                float d0 = q4.x - xr[0], d1 = q4.y - xr[1];
                float d2 = q4.z - xr[2], d3 = q4.w - xr[3];
                sqAcc = fmaf(d0, d0, sqAcc); sqAcc = fmaf(d1, d1, sqAcc);
                sqAcc = fmaf(d2, d2, sqAcc); sqAcc = fmaf(d3, d3, sqAcc);
                op[(size_t)(d + 0) * 1024] = q4.x;
                op[(size_t)(d + 1) * 1024] = q4.y;
                op[(size_t)(d + 2) * 1024] = q4.z;
                op[(size_t)(d + 3) * 1024] = q4.w;
            }
        }
        if (t < 16) {
            int tok = ch * 16 + t;
            out[IDX_OFF + n0 + tok] = (float)wIdxS[tok];
            atomicAdd(&counts[wIdxS[tok]], 1);
        }
    }
    float sq = sqAcc;
    #pragma unroll
    for (int m = 32; m > 0; m >>= 1) sq += __shfl_down(sq, m, 64);
    if (lane == 0) lred[wv] = sq;
    __syncthreads();
    if (t == 0) partials[wg] = (lred[0] + lred[1]) + (lred[2] + lred[3]);
}

// ---------------- fallback (verified R2 path, small ws) ----------------
#define TM 64
#define TN 64
#define DK 32
#define WS_PAD 68
__global__ __launch_bounds__(256, 2)
void vq_main_fb(const float* __restrict__ x, const float* __restrict__ wt,
                float* __restrict__ out, int* __restrict__ counts,
                float* __restrict__ partials) {
    __shared__ float As[DIM][TM];
    __shared__ float Ws[DK][WS_PAD];
    __shared__ float minv[TM];
    __shared__ int   mini[TM];
    __shared__ float sxp[4][TM];
    __shared__ float sxv[TM];
    __shared__ float lred[4];
    const int t = threadIdx.x, wg = blockIdx.x;
    const int n0 = wg * TM, b = n0 >> 10, p0 = n0 & 1023;
    const float* xb = x + (size_t)b * DIM * 1024 + p0;
    #pragma unroll
    for (int i = 0; i < 16; ++i) {
        int c = t + 256 * i, d = c >> 4, pg = (c & 15) << 2;
        *reinterpret_cast<float4*>(&As[d][pg]) =
            *reinterpret_cast<const float4*>(xb + (size_t)d * 1024 + pg);
    }
    if (t < TM) { minv[t] = 3.0e38f; mini[t] = 0; }
    __syncthreads();
    {
        int tok = t & 63, w = t >> 6;
        float p = 0.0f;
        #pragma unroll
        for (int d = 0; d < 64; ++d) { float v = As[w * 64 + d][tok]; p = fmaf(v, v, p); }
        sxp[w][tok] = p;
    }
    __syncthreads();
    if (t < TM) sxv[t] = (sxp[0][t] + sxp[1][t]) + (sxp[2][t] + sxp[3][t]);
    const int tx = t & 15, ty = t >> 4;
    for (int k0 = 0; k0 < NUME; k0 += TN) {
        float acc[4][4];
        #pragma unroll
        for (int i = 0; i < 4; ++i)
            #pragma unroll
            for (int j = 0; j < 4; ++j) acc[i][j] = 0.0f;
        for (int d0 = 0; d0 < DIM; d0 += DK) {
            __syncthreads();
            int r = t >> 3, dc = (t & 7) << 2;
            #pragma unroll
            for (int h = 0; h < 2; ++h) {
                float4 v = *reinterpret_cast<const float4*>(
                    wt + (size_t)(k0 + r + 32 * h) * DIM + d0 + dc);
                Ws[dc + 0][r + 32 * h] = v.x; Ws[dc + 1][r + 32 * h] = v.y;
                Ws[dc + 2][r + 32 * h] = v.z; Ws[dc + 3][r + 32 * h] = v.w;
            }
            __syncthreads();
            #pragma unroll
            for (int dd = 0; dd < DK; ++dd) {
                float4 a = *reinterpret_cast<const float4*>(&As[d0 + dd][ty << 2]);
                float4 w = *reinterpret_cast<const float4*>(&Ws[dd][tx << 2]);
                float av[4] = {a.x, a.y, a.z, a.w}, wv2[4] = {w.x, w.y, w.z, w.w};
                #pragma unroll
                for (int i = 0; i < 4; ++i)
                    #pragma unroll
                    for (int j = 0; j < 4; ++j) acc[i][j] = fmaf(av[i], wv2[j], acc[i][j]);
            }
        }
        #pragma unroll
        for (int i = 0; i < 4; ++i) {
            float sxt = sxv[(ty << 2) + i];
            float bv = 3.0e38f; int bi = 0;
            #pragma unroll
            for (int j = 0; j < 4; ++j) {
                float s = sxt - 2.0f * acc[i][j];
                int gi = k0 + (tx << 2) + j;
                if (s < bv) { bv = s; bi = gi; }
            }
            #pragma unroll
            for (int m = 1; m < 16; m <<= 1) {
                float ov = __shfl_xor(bv, m, 64); int oi = __shfl_xor(bi, m, 64);
                if (ov < bv || (ov == bv && oi < bi)) { bv = ov; bi = oi; }
            }
            if (tx == 0) {
                int pl = (ty << 2) + i;
                if (bv < minv[pl]) { minv[pl] = bv; mini[pl] = bi; }
            }
        }
    }
    __syncthreads();
    const int pg = (t & 15) << 2, db = t >> 4;
    int idx4[4];
    #pragma unroll
    for (int j = 0; j < 4; ++j) idx4[j] = mini[pg + j];
    float* outq = out + (size_t)b * DIM * 1024 + p0;
    float sq = 0.0f;
    #pragma unroll
    for (int i = 0; i < 16; ++i) {
        int d = db + (i << 4);
        float4 qv;
        qv.x = wt[(size_t)idx4[0] * DIM + d]; qv.y = wt[(size_t)idx4[1] * DIM + d];
        qv.z = wt[(size_t)idx4[2] * DIM + d]; qv.w = wt[(size_t)idx4[3] * DIM + d];
        float4 xa = *reinterpret_cast<const float4*>(&As[d][pg]);
        float d0_ = qv.x - xa.x, d1_ = qv.y - xa.y, d2_ = qv.z - xa.z, d3_ = qv.w - xa.w;
        sq = fmaf(d0_, d0_, sq); sq = fmaf(d1_, d1_, sq);
        sq = fmaf(d2_, d2_, sq); sq = fmaf(d3_, d3_, sq);
        *reinterpret_cast<float4*>(outq + (size_t)d * 1024 + pg) = qv;
    }
    const int lane = t & 63, wid = t >> 6;
    #pragma unroll
    for (int m = 32; m > 0; m >>= 1) sq += __shfl_down(sq, m, 64);
    if (lane == 0) lred[wid] = sq;
    __syncthreads();
    if (t == 0) partials[wg] = (lred[0] + lred[1]) + (lred[2] + lred[3]);
    if (t < TM) {
        atomicAdd(&counts[mini[t]], 1);
        out[IDX_OFF + n0 + t] = (float)mini[t];
    }
}

// ---------------- finalize loss + perplexity ----------------
__global__ void vq_final(const int* __restrict__ counts,
                         const float* __restrict__ partials,
                         float* __restrict__ out) {
    __shared__ float red[256];
    int t = threadIdx.x;
    red[t] = partials[t] + partials[t + 256];
    __syncthreads();
    for (int m = 128; m > 0; m >>= 1) {
        if (t < m) red[t] += red[t + m];
        __syncthreads();
    }
    if (t == 0) out[LOSS_OFF] = 1.25f * red[0] / (float)NELEM;
    __syncthreads();
    float e = 0.0f;
    for (int c = t; c < NUME; c += 256) {
        float p = (float)counts[c] * (1.0f / (float)NTOK);
        e += p * logf(p + 1e-10f);
    }
    red[t] = e;
    __syncthreads();
    for (int m = 128; m > 0; m >>= 1) {
        if (t < m) red[t] += red[t + m];
        __syncthreads();
    }
    if (t == 0) out[PERP_OFF] = expf(-red[0]);
}

extern "C" void kernel_launch(void* const* d_in, const int* in_sizes, int n_in,
                              void* d_out, int out_size, void* d_ws, size_t ws_size,
                              hipStream_t stream) {
    const float* x  = (const float*)d_in[0];
    const float* wt = (const float*)d_in[1];
    float* out = (float*)d_out;
    const size_t WB_BYTES = (size_t)NUME * DIM;               // 1 MB i8 codebook
    const size_t NEED = WB_BYTES + 16384 + 2048;

    if (ws_size >= NEED) {
        uint8_t* wb   = (uint8_t*)d_ws;
        int* counts   = (int*)((char*)d_ws + WB_BYTES);
        float* partials = (float*)((char*)d_ws + WB_BYTES + 16384);
        hipMemsetAsync((char*)d_ws + WB_BYTES, 0, 16384 + 2048, stream);
        vq_prep<<<512, 256, 0, stream>>>(wt, wb);
        vq_mfma<<<512, 256, 0, stream>>>(x, wt, wb, out, counts, partials);
        vq_final<<<1, 256, 0, stream>>>(counts, partials, out);
    } else {
        int* counts   = (int*)d_ws;
        float* partials = (float*)((char*)d_ws + 16384);
        hipMemsetAsync(d_ws, 0, 16384 + 2048, stream);
        vq_main_fb<<<NTOK / TM, 256, 0, stream>>>(x, wt, out, counts, partials);
        vq_final<<<1, 256, 0, stream>>>(counts, partials, out);
    }
}

// Round 14
// 176.000 us; speedup vs baseline: 12.5211x; 12.5211x over previous
//
#include <hip/hip_runtime.h>
#include <math.h>
#include <stdint.h>

#define DIM 256
#define NUME 4096
#define NTOK 32768
#define NELEM 8388608        // 32*256*32*32
#define LOSS_OFF 8388608
#define PERP_OFF 8388609
#define IDX_OFF  8388610
#define MARGIN   4.0e-4f     // score-space margin (verified R3/R8/R10/R11)
#define ATHR_PAD 1.0e-4f     // extra m-space pad
#define CAND_CAP 48
#define BOOT_TILES 32        // bootstrap sample: 2048 codes

using short8 = __attribute__((ext_vector_type(8))) short;
using f32x16 = __attribute__((ext_vector_type(16))) float;

// counted-wait primitives (m201-verified pattern; sched_barrier per rule #18)
#define WAIT_VM8()   do { asm volatile("s_waitcnt vmcnt(8)" ::: "memory"); \
                          __builtin_amdgcn_sched_barrier(0); } while (0)
#define WAIT_VM0()   do { asm volatile("s_waitcnt vmcnt(0)" ::: "memory"); \
                          __builtin_amdgcn_sched_barrier(0); } while (0)
#define WAIT_LGKM0() do { asm volatile("s_waitcnt lgkmcnt(0)" ::: "memory"); \
                          __builtin_amdgcn_sched_barrier(0); } while (0)
#define BAR()        __builtin_amdgcn_s_barrier()

__device__ __forceinline__ uint16_t f2bf(float f) {           // RNE f32->bf16
    uint32_t u = __float_as_uint(f);
    u += 0x7FFFu + ((u >> 16) & 1u);
    return (uint16_t)(u >> 16);
}
__device__ __forceinline__ void gload_lds16(const void* g, void* l) {
    __builtin_amdgcn_global_load_lds(
        (const __attribute__((address_space(1))) void*)g,
        (__attribute__((address_space(3))) void*)l, 16, 0, 0);
}

// ---------------- prep: W fp32 -> bf16 [4096][256] ----------------
__global__ void vq_prep(const float* __restrict__ w, uint16_t* __restrict__ wb) {
    int gid = blockIdx.x * 256 + threadIdx.x;       // 131072 threads x 8 elems
    const float4* src = (const float4*)(w + (size_t)gid * 8);
    float4 a = src[0], c = src[1];
    uint4 o;
    o.x = (uint32_t)f2bf(a.x) | ((uint32_t)f2bf(a.y) << 16);
    o.y = (uint32_t)f2bf(a.z) | ((uint32_t)f2bf(a.w) << 16);
    o.z = (uint32_t)f2bf(c.x) | ((uint32_t)f2bf(c.y) << 16);
    o.w = (uint32_t)f2bf(c.z) | ((uint32_t)f2bf(c.w) << 16);
    *(uint4*)(wb + (size_t)gid * 8) = o;
}

// ---- main: fused x-pass -> 32-tile bootstrap -> fixed threshold -> 64-tile
//      collect sweep (R11-verbatim screen) -> group-parallel exact fp32 rescore ----
__global__ __launch_bounds__(256, 2)
void vq_mfma(const float* __restrict__ x, const float* __restrict__ wt,
             const uint16_t* __restrict__ wb, float* __restrict__ out,
             int* __restrict__ counts, float* __restrict__ partials) {
    __shared__ __align__(16) char UB[65536];   // union: Xbf16 / W dbuf / Xf32 chunk
    __shared__ float sxp[4][64];
    __shared__ float sxS[64];
    __shared__ unsigned gmU[64];
    __shared__ unsigned candCnt[64];
    __shared__ unsigned candL[64 * CAND_CAP];
    __shared__ int wIdxS[64];
    __shared__ float lred[4];

    const int t    = threadIdx.x;
    const int lane = t & 63;
    const int wv   = t >> 6;                 // wave 0..3
    const int wr   = wv >> 1, wc = wv & 1;   // wave grid 2x2 (32 tok x 32 code)
    const int l31  = lane & 31, hh = lane >> 5;
    const int wg   = blockIdx.x;
    const int n0   = wg << 6;
    const int b    = n0 >> 10;
    const int p0   = n0 & 1023;
    const float* xbase = x + (size_t)b * (DIM * 1024) + p0;

    if (t < 64) { gmU[t] = 0x7F7FFFFFu; candCnt[t] = 0; }

    // ---- S0' (fused): single x pass -> sx partial + bf16 LDS (swizzled) ----
    {
        int tok = t & 63, w8 = t >> 6;
        const float* p = xbase + (size_t)(w8 * 64) * 1024 + tok;
        float s = 0.f;
        #pragma unroll
        for (int d = 0; d < 64; ++d) {
            float v = p[(size_t)d * 1024];
            s = fmaf(v, v, s);
            int byte = (tok << 9) + ((w8 * 64 + d) << 1);
            byte ^= ((tok & 15) << 4);
            *(uint16_t*)(UB + byte) = f2bf(v);
        }
        sxp[w8][tok] = s;
    }
    __syncthreads();
    if (t < 64) sxS[t] = (sxp[0][t] + sxp[1][t]) + (sxp[2][t] + sxp[3][t]);

    // ---- S2: A-frags (32x32x16 layout) resident in registers ----
    short8 aF[16];
    #pragma unroll
    for (int ks = 0; ks < 16; ++ks) {
        int row = wr * 32 + l31;
        int byte = (row << 9) + (ks << 5) + (hh << 4);
        byte ^= ((row & 15) << 4);
        aF[ks] = *(const short8*)(UB + byte);
    }
    __syncthreads();   // Xbf dead; UB free for W staging

    auto STAGE = [&](int k0, int half) {
        #pragma unroll
        for (int i = 0; i < 8; ++i) {
            int o16 = i * 256 + t;
            int code = o16 >> 5, u = o16 & 31;
            const char* src = (const char*)wb + ((size_t)(k0 + code) << 9)
                              + ((u ^ (code & 15)) << 4);
            gload_lds16(src, UB + (half << 15) + (o16 << 4));
        }
    };

    // ---- bootstrap: tiles 0..31, pure register fmax; depth-2 pipeline ----
    float run[16];
    #pragma unroll
    for (int rg = 0; rg < 16; ++rg) run[rg] = -3.0e38f;

    STAGE(0, 0);
    STAGE(64, 1);
    for (int tile = 0; tile < BOOT_TILES; ++tile) {
        if (tile < BOOT_TILES - 1) WAIT_VM8(); else WAIT_VM0();
        BAR();
        const int half = tile & 1;

        f32x16 acc = {0.f,0.f,0.f,0.f,0.f,0.f,0.f,0.f,
                      0.f,0.f,0.f,0.f,0.f,0.f,0.f,0.f};
        const int cr = wc * 32 + l31;
        const int bbase = (half << 15) + (cr << 9) + (hh << 4);
        const int bxor  = ((cr & 15) << 4);
        #pragma unroll
        for (int ks = 0; ks < 16; ++ks) {
            short8 bF = *(const short8*)(UB + ((bbase + (ks << 5)) ^ bxor));
            acc = __builtin_amdgcn_mfma_f32_32x32x16_bf16(aF[ks], bF, acc, 0, 0, 0);
        }
        #pragma unroll
        for (int rg = 0; rg < 16; ++rg) run[rg] = fmaxf(run[rg], acc[rg]);

        WAIT_LGKM0();
        BAR();
        if (tile + 2 < BOOT_TILES) STAGE((tile + 2) * 64, half);
    }

    // reduce bootstrap row maxes over the 32 lanes sharing each row
    #pragma unroll
    for (int rg = 0; rg < 16; ++rg) {
        float m = run[rg];
        #pragma unroll
        for (int sh = 1; sh < 32; sh <<= 1) m = fmaxf(m, __shfl_xor(m, sh, 64));
        if (l31 == 0) {
            int row = wr * 32 + (rg & 3) + 8 * (rg >> 2) + 4 * hh;
            float s = sxS[row] - 2.0f * m;      // s-space lower-bound via subsample max
            atomicMin(&gmU[row], __float_as_uint(s));
        }
    }
    __syncthreads();

    // fixed conservative threshold: thrA = L2048 - MARGIN/2 - PAD  (<= trueMax - window)
    float athr[16];
    #pragma unroll
    for (int rg = 0; rg < 16; ++rg) {
        int row = wr * 32 + (rg & 3) + 8 * (rg >> 2) + 4 * hh;
        athr[rg] = 0.5f * (sxS[row] - (__uint_as_float(gmU[row]) + MARGIN)) - ATHR_PAD;
    }

    // ---- collect sweep: all 64 tiles vs FIXED threshold; depth-2 pipeline ----
    STAGE(0, 0);
    STAGE(64, 1);
    for (int tile = 0; tile < 64; ++tile) {
        if (tile < 63) WAIT_VM8(); else WAIT_VM0();
        BAR();
        const int half = tile & 1;

        f32x16 acc = {0.f,0.f,0.f,0.f,0.f,0.f,0.f,0.f,
                      0.f,0.f,0.f,0.f,0.f,0.f,0.f,0.f};
        const int cr = wc * 32 + l31;
        const int bbase = (half << 15) + (cr << 9) + (hh << 4);
        const int bxor  = ((cr & 15) << 4);
        #pragma unroll
        for (int ks = 0; ks < 16; ++ks) {
            short8 bF = *(const short8*)(UB + ((bbase + (ks << 5)) ^ bxor));
            acc = __builtin_amdgcn_mfma_f32_32x32x16_bf16(aF[ks], bF, acc, 0, 0, 0);
        }
        #pragma unroll
        for (int rg = 0; rg < 16; ++rg) {
            if (acc[rg] >= athr[rg]) {
                int row = wr * 32 + (rg & 3) + 8 * (rg >> 2) + 4 * hh;
                int code = tile * 64 + wc * 32 + l31;
                unsigned s = atomicAdd(&candCnt[row], 1u);
                if (s < CAND_CAP) candL[row * CAND_CAP + s] = (unsigned)code;
            }
        }

        WAIT_LGKM0();
        BAR();
        if (tile + 2 < 64) STAGE((tile + 2) * 64, half);
    }

    // ---- chunked exact fp32 rescore (group-parallel) + fused epilogue ----
    float sqAcc = 0.f;
    for (int ch = 0; ch < 2; ++ch) {
        __syncthreads();
        {   // stage Xf32 [32][258] (padded) into UB
            int dg = t >> 2, c = t & 3;
            #pragma unroll
            for (int it = 0; it < 4; ++it) {
                int d = it * 64 + dg;
                const float* row = xbase + (size_t)d * 1024 + ch * 32 + c * 8;
                float4 f0 = *(const float4*)(row);
                float4 f1 = *(const float4*)(row + 4);
                float vv[8] = {f0.x, f0.y, f0.z, f0.w, f1.x, f1.y, f1.z, f1.w};
                #pragma unroll
                for (int j = 0; j < 8; ++j) {
                    int tl = c * 8 + j;
                    *(float*)(UB + ((tl * 258 + d) << 2)) = vv[j];
                }
            }
        }
        __syncthreads();
        // group-parallel rescore: 16-lane groups, 4 tokens/wave in flight.
        // reference-exact fl(sx - 2*dot), strict-less + lowest-index ties.
        {
            const int grp = lane >> 4, gl = lane & 15;
            #pragma unroll
            for (int ti = 0; ti < 2; ++ti) {
                int tl = wv * 4 + grp + ti * 16;      // 0..31 within chunk
                int tok = ch * 32 + tl;
                unsigned ncnt = candCnt[tok];
                int nc = (ncnt > CAND_CAP) ? 0 : (int)ncnt;   // ovf -> uniform path
                float xr[16];
                const float* xs = (const float*)UB + tl * 258 + gl * 16;
                #pragma unroll
                for (int j = 0; j < 16; ++j) xr[j] = xs[j];
                float sxt = sxS[tok];
                float bs = 3.0e38f; int bi = 0;
                for (int ci = 0; ci < nc; ++ci) {
                    int code = (int)candL[tok * CAND_CAP + ci];
                    const float* wr_ = wt + (size_t)code * 256 + gl * 16;
                    float p = 0.f;
                    #pragma unroll
                    for (int j = 0; j < 4; ++j) {
                        float4 w4 = *(const float4*)(wr_ + 4 * j);
                        p = fmaf(w4.x, xr[4 * j + 0], p);
                        p = fmaf(w4.y, xr[4 * j + 1], p);
                        p = fmaf(w4.z, xr[4 * j + 2], p);
                        p = fmaf(w4.w, xr[4 * j + 3], p);
                    }
                    #pragma unroll
                    for (int sh = 1; sh < 16; sh <<= 1) p += __shfl_xor(p, sh, 64);
                    float s = sxt - 2.0f * p;
                    if (s < bs || (s == bs && code < bi)) { bs = s; bi = code; }
                }
                if (gl == 0 && nc > 0) wIdxS[tok] = bi;
            }
            // rare overflow: wave-uniform exact full scan (old 64-lane path)
            for (int tt = 0; tt < 8; ++tt) {
                int tl = wv * 4 + (tt & 3) + (tt >> 2) * 16;
                int tok = ch * 32 + tl;
                if (candCnt[tok] > CAND_CAP) {
                    float bs = 3.0e38f; int bi = 0;
                    for (int code = 0; code < NUME; ++code) {
                        float4 wv4 = *(const float4*)(wt + (size_t)code * 256 + lane * 4);
                        const float* xr2 = (const float*)UB + tl * 258 + lane * 4;
                        float p = wv4.x * xr2[0];
                        p = fmaf(wv4.y, xr2[1], p);
                        p = fmaf(wv4.z, xr2[2], p);
                        p = fmaf(wv4.w, xr2[3], p);
                        #pragma unroll
                        for (int sh = 1; sh < 64; sh <<= 1) p += __shfl_xor(p, sh, 64);
                        float s = sxS[tok] - 2.0f * p;
                        if (s < bs || (s == bs && code < bi)) { bs = s; bi = code; }
                    }
                    if (lane == 0) wIdxS[tok] = bi;
                }
            }
        }
        __syncthreads();
        {   // gather + quantized write + loss partial
            int tl = t & 31, db = (t >> 5) * 32;
            int idx = wIdxS[ch * 32 + tl];
            const float* wrow = wt + (size_t)idx * 256;
            float* op = out + (size_t)b * (DIM * 1024) + p0 + ch * 32 + tl;
            #pragma unroll
            for (int j = 0; j < 8; ++j) {
                int d = db + 4 * j;
                float4 q4 = *(const float4*)(wrow + d);
                const float* xr = (const float*)(UB + ((tl * 258 + d) << 2));
                float d0 = q4.x - xr[0], d1 = q4.y - xr[1];
                float d2 = q4.z - xr[2], d3 = q4.w - xr[3];
                sqAcc = fmaf(d0, d0, sqAcc); sqAcc = fmaf(d1, d1, sqAcc);
                sqAcc = fmaf(d2, d2, sqAcc); sqAcc = fmaf(d3, d3, sqAcc);
                op[(size_t)(d + 0) * 1024] = q4.x;
                op[(size_t)(d + 1) * 1024] = q4.y;
                op[(size_t)(d + 2) * 1024] = q4.z;
                op[(size_t)(d + 3) * 1024] = q4.w;
            }
        }
        if (t < 32) {
            int tok = ch * 32 + t;
            out[IDX_OFF + n0 + tok] = (float)wIdxS[tok];
            atomicAdd(&counts[wIdxS[tok]], 1);
        }
    }
    float sq = sqAcc;
    #pragma unroll
    for (int m = 32; m > 0; m >>= 1) sq += __shfl_down(sq, m, 64);
    if (lane == 0) lred[wv] = sq;
    __syncthreads();
    if (t == 0) partials[wg] = (lred[0] + lred[1]) + (lred[2] + lred[3]);
}

// ---------------- fallback (verified R2 path, small ws) ----------------
#define TM 64
#define TN 64
#define DK 32
#define WS_PAD 68
__global__ __launch_bounds__(256, 2)
void vq_main_fb(const float* __restrict__ x, const float* __restrict__ wt,
                float* __restrict__ out, int* __restrict__ counts,
                float* __restrict__ partials) {
    __shared__ float As[DIM][TM];
    __shared__ float Ws[DK][WS_PAD];
    __shared__ float minv[TM];
    __shared__ int   mini[TM];
    __shared__ float sxp[4][TM];
    __shared__ float sxv[TM];
    __shared__ float lred[4];
    const int t = threadIdx.x, wg = blockIdx.x;
    const int n0 = wg * TM, b = n0 >> 10, p0 = n0 & 1023;
    const float* xb = x + (size_t)b * DIM * 1024 + p0;
    #pragma unroll
    for (int i = 0; i < 16; ++i) {
        int c = t + 256 * i, d = c >> 4, pg = (c & 15) << 2;
        *reinterpret_cast<float4*>(&As[d][pg]) =
            *reinterpret_cast<const float4*>(xb + (size_t)d * 1024 + pg);
    }
    if (t < TM) { minv[t] = 3.0e38f; mini[t] = 0; }
    __syncthreads();
    {
        int tok = t & 63, w = t >> 6;
        float p = 0.0f;
        #pragma unroll
        for (int d = 0; d < 64; ++d) { float v = As[w * 64 + d][tok]; p = fmaf(v, v, p); }
        sxp[w][tok] = p;
    }
    __syncthreads();
    if (t < TM) sxv[t] = (sxp[0][t] + sxp[1][t]) + (sxp[2][t] + sxp[3][t]);
    const int tx = t & 15, ty = t >> 4;
    for (int k0 = 0; k0 < NUME; k0 += TN) {
        float acc[4][4];
        #pragma unroll
        for (int i = 0; i < 4; ++i)
            #pragma unroll
            for (int j = 0; j < 4; ++j) acc[i][j] = 0.0f;
        for (int d0 = 0; d0 < DIM; d0 += DK) {
            __syncthreads();
            int r = t >> 3, dc = (t & 7) << 2;
            #pragma unroll
            for (int h = 0; h < 2; ++h) {
                float4 v = *reinterpret_cast<const float4*>(
                    wt + (size_t)(k0 + r + 32 * h) * DIM + d0 + dc);
                Ws[dc + 0][r + 32 * h] = v.x; Ws[dc + 1][r + 32 * h] = v.y;
                Ws[dc + 2][r + 32 * h] = v.z; Ws[dc + 3][r + 32 * h] = v.w;
            }
            __syncthreads();
            #pragma unroll
            for (int dd = 0; dd < DK; ++dd) {
                float4 a = *reinterpret_cast<const float4*>(&As[d0 + dd][ty << 2]);
                float4 w = *reinterpret_cast<const float4*>(&Ws[dd][tx << 2]);
                float av[4] = {a.x, a.y, a.z, a.w}, wv2[4] = {w.x, w.y, w.z, w.w};
                #pragma unroll
                for (int i = 0; i < 4; ++i)
                    #pragma unroll
                    for (int j = 0; j < 4; ++j) acc[i][j] = fmaf(av[i], wv2[j], acc[i][j]);
            }
        }
        #pragma unroll
        for (int i = 0; i < 4; ++i) {
            float sxt = sxv[(ty << 2) + i];
            float bv = 3.0e38f; int bi = 0;
            #pragma unroll
            for (int j = 0; j < 4; ++j) {
                float s = sxt - 2.0f * acc[i][j];
                int gi = k0 + (tx << 2) + j;
                if (s < bv) { bv = s; bi = gi; }
            }
            #pragma unroll
            for (int m = 1; m < 16; m <<= 1) {
                float ov = __shfl_xor(bv, m, 64); int oi = __shfl_xor(bi, m, 64);
                if (ov < bv || (ov == bv && oi < bi)) { bv = ov; bi = oi; }
            }
            if (tx == 0) {
                int pl = (ty << 2) + i;
                if (bv < minv[pl]) { minv[pl] = bv; mini[pl] = bi; }
            }
        }
    }
    __syncthreads();
    const int pg = (t & 15) << 2, db = t >> 4;
    int idx4[4];
    #pragma unroll
    for (int j = 0; j < 4; ++j) idx4[j] = mini[pg + j];
    float* outq = out + (size_t)b * DIM * 1024 + p0;
    float sq = 0.0f;
    #pragma unroll
    for (int i = 0; i < 16; ++i) {
        int d = db + (i << 4);
        float4 qv;
        qv.x = wt[(size_t)idx4[0] * DIM + d]; qv.y = wt[(size_t)idx4[1] * DIM + d];
        qv.z = wt[(size_t)idx4[2] * DIM + d]; qv.w = wt[(size_t)idx4[3] * DIM + d];
        float4 xa = *reinterpret_cast<const float4*>(&As[d][pg]);
        float d0_ = qv.x - xa.x, d1_ = qv.y - xa.y, d2_ = qv.z - xa.z, d3_ = qv.w - xa.w;
        sq = fmaf(d0_, d0_, sq); sq = fmaf(d1_, d1_, sq);
        sq = fmaf(d2_, d2_, sq); sq = fmaf(d3_, d3_, sq);
        *reinterpret_cast<float4*>(outq + (size_t)d * 1024 + pg) = qv;
    }
    const int lane = t & 63, wid = t >> 6;
    #pragma unroll
    for (int m = 32; m > 0; m >>= 1) sq += __shfl_down(sq, m, 64);
    if (lane == 0) lred[wid] = sq;
    __syncthreads();
    if (t == 0) partials[wg] = (lred[0] + lred[1]) + (lred[2] + lred[3]);
    if (t < TM) {
        atomicAdd(&counts[mini[t]], 1);
        out[IDX_OFF + n0 + t] = (float)mini[t];
    }
}

// ---------------- finalize loss + perplexity ----------------
__global__ void vq_final(const int* __restrict__ counts,
                         const float* __restrict__ partials,
                         float* __restrict__ out) {
    __shared__ float red[256];
    int t = threadIdx.x;
    red[t] = partials[t] + partials[t + 256];
    __syncthreads();
    for (int m = 128; m > 0; m >>= 1) {
        if (t < m) red[t] += red[t + m];
        __syncthreads();
    }
    if (t == 0) out[LOSS_OFF] = 1.25f * red[0] / (float)NELEM;
    __syncthreads();
    float e = 0.0f;
    for (int c = t; c < NUME; c += 256) {
        float p = (float)counts[c] * (1.0f / (float)NTOK);
        e += p * logf(p + 1e-10f);
    }
    red[t] = e;
    __syncthreads();
    for (int m = 128; m > 0; m >>= 1) {
        if (t < m) red[t] += red[t + m];
        __syncthreads();
    }
    if (t == 0) out[PERP_OFF] = expf(-red[0]);
}

extern "C" void kernel_launch(void* const* d_in, const int* in_sizes, int n_in,
                              void* d_out, int out_size, void* d_ws, size_t ws_size,
                              hipStream_t stream) {
    const float* x  = (const float*)d_in[0];
    const float* wt = (const float*)d_in[1];
    float* out = (float*)d_out;
    const size_t WB_BYTES = (size_t)NUME * DIM * 2;           // 2 MB bf16 codebook
    const size_t NEED = WB_BYTES + 16384 + 2048;

    if (ws_size >= NEED) {
        uint16_t* wb  = (uint16_t*)d_ws;
        int* counts   = (int*)((char*)d_ws + WB_BYTES);
        float* partials = (float*)((char*)d_ws + WB_BYTES + 16384);
        hipMemsetAsync((char*)d_ws + WB_BYTES, 0, 16384 + 2048, stream);
        vq_prep<<<512, 256, 0, stream>>>(wt, wb);
        vq_mfma<<<512, 256, 0, stream>>>(x, wt, wb, out, counts, partials);
        vq_final<<<1, 256, 0, stream>>>(counts, partials, out);
    } else {
        int* counts   = (int*)d_ws;
        float* partials = (float*)((char*)d_ws + 16384);
        hipMemsetAsync(d_ws, 0, 16384 + 2048, stream);
        vq_main_fb<<<NTOK / TM, 256, 0, stream>>>(x, wt, out, counts, partials);
        vq_final<<<1, 256, 0, stream>>>(counts, partials, out);
    }
}